// Round 2
// baseline (889.612 us; speedup 1.0000x reference)
//
#include <hip/hip_runtime.h>
#include <math.h>

#define NB 16
#define NT 12
#define NN 2048
#define NH 16
#define NK 20

// ---- k_topk config ----
#define RPW 4               // rows per wave
#define WPB 4               // waves per block
#define RPB (RPW * WPB)     // 16 rows per block
#define CHUNK 256
#define NCH (NN / CHUNK)    // 8
#define JST (CHUNK / 64)    // 4
#define EST 20              // padded float stride per node in LDS
#define CCAP 64

static __device__ __forceinline__ unsigned long long shflxor64(unsigned long long v, int m) {
  unsigned lo = (unsigned)v, hi = (unsigned)(v >> 32);
  lo = (unsigned)__shfl_xor((int)lo, m, 64);
  hi = (unsigned)__shfl_xor((int)hi, m, 64);
  return ((unsigned long long)hi << 32) | lo;
}

static __device__ __forceinline__ float rfl(float v) {
  return __int_as_float(__builtin_amdgcn_readfirstlane(__float_as_int(v)));
}

// ---- kernel 0: state mean + 16-dim tanh embedding -------------------------
__global__ void k_emb(const float* __restrict__ x, const float* __restrict__ W,
                      const float* __restrict__ bias, float* __restrict__ emb) {
  int id = blockIdx.x * blockDim.x + threadIdx.x;
  if (id >= NB * NN) return;
  int b = id >> 11, n = id & (NN - 1);
  const float* xp = x + ((size_t)b * NT) * NN + n;
  float s = 0.0f;
#pragma unroll
  for (int t = 0; t < NT; ++t) s += xp[(size_t)t * NN];
  s = s / 12.0f;
  float* e = emb + (size_t)id * NH;
#pragma unroll
  for (int h = 0; h < NH; ++h) {
    float arg = __fadd_rn(__fmul_rn(s, W[h]), bias[h]);
    e[h] = (float)tanh((double)arg);
  }
}

// ---- kernel 1: A_physical row sums -> a / (sum + 1e-8) --------------------
__global__ void k_rowsum(const float* __restrict__ A, const float* __restrict__ alpha,
                         float* __restrict__ aInv) {
  int gw = (blockIdx.x * blockDim.x + threadIdx.x) >> 6;
  int lane = threadIdx.x & 63;
  if (gw >= NN) return;
  const float* row = A + (size_t)gw * NN;
  float s = 0.0f;
#pragma unroll
  for (int j = 0; j < NN / 64; ++j) s += row[lane + 64 * j];
#pragma unroll
  for (int off = 32; off; off >>= 1) s += __shfl_xor(s, off, 64);
  if (lane == 0) {
    float a = 1.0f / (1.0f + expf(-alpha[0]));
    aInv[gw] = a / (s + 1e-8f);
  }
}

// ---- kernel 2: dots + exact top-20 + softmax -> (idx, final fix value) ----
__global__ __launch_bounds__(256, 2) void k_topk(
    const float* __restrict__ emb, const float* __restrict__ Ap,
    const float* __restrict__ aInv, const float* __restrict__ alpha,
    unsigned short* __restrict__ fixIdx, float* __restrict__ fixVal) {
  __shared__ float se[CHUNK * EST];                 // 20480 B
  __shared__ unsigned long long cand[WPB][CCAP];    // 2048 B

  const int tid = threadIdx.x;
  const int lane = tid & 63;
  const int wv = tid >> 6;
  const int b = blockIdx.x >> 7;        // 128 blocks per batch
  const int nbase = (blockIdx.x & 127) * RPB;
  const float* embB = emb + (size_t)b * NN * NH;

  // query embeddings -> wave-uniform scalars (SGPRs)
  float en[RPW][NH];
#pragma unroll
  for (int r = 0; r < RPW; ++r) {
    const float* ep = embB + (size_t)(nbase + wv * RPW + r) * NH;
    float4 t0 = *(const float4*)(ep + 0);
    float4 t1 = *(const float4*)(ep + 4);
    float4 t2 = *(const float4*)(ep + 8);
    float4 t3 = *(const float4*)(ep + 12);
    en[r][0] = rfl(t0.x); en[r][1] = rfl(t0.y); en[r][2] = rfl(t0.z); en[r][3] = rfl(t0.w);
    en[r][4] = rfl(t1.x); en[r][5] = rfl(t1.y); en[r][6] = rfl(t1.z); en[r][7] = rfl(t1.w);
    en[r][8] = rfl(t2.x); en[r][9] = rfl(t2.y); en[r][10] = rfl(t2.z); en[r][11] = rfl(t2.w);
    en[r][12] = rfl(t3.x); en[r][13] = rfl(t3.y); en[r][14] = rfl(t3.z); en[r][15] = rfl(t3.w);
  }

  float g[RPW][32];
  float lmax[RPW];
#pragma unroll
  for (int r = 0; r < RPW; ++r) lmax[r] = -1.0f;

#pragma unroll
  for (int c = 0; c < NCH; ++c) {
    __syncthreads();
    // stage: thread t loads quarter (t&3) of node (t>>2)+64k -> 16B/lane contiguous
#pragma unroll
    for (int k = 0; k < 4; ++k) {
      int node = (tid >> 2) + 64 * k;
      float4 v = *(const float4*)(embB + (size_t)(c * CHUNK + node) * NH + (tid & 3) * 4);
      *(float4*)(se + node * EST + (tid & 3) * 4) = v;
    }
    __syncthreads();
#pragma unroll
    for (int j = 0; j < JST; ++j) {
      const float* em = se + (size_t)(j * 64 + lane) * EST;
      float4 e0 = *(const float4*)(em + 0);
      float4 e1 = *(const float4*)(em + 4);
      float4 e2 = *(const float4*)(em + 8);
      float4 e3 = *(const float4*)(em + 12);
#pragma unroll
      for (int r = 0; r < RPW; ++r) {
        float acc = 0.0f;
        acc = __fmaf_rn(en[r][0], e0.x, acc);
        acc = __fmaf_rn(en[r][1], e0.y, acc);
        acc = __fmaf_rn(en[r][2], e0.z, acc);
        acc = __fmaf_rn(en[r][3], e0.w, acc);
        acc = __fmaf_rn(en[r][4], e1.x, acc);
        acc = __fmaf_rn(en[r][5], e1.y, acc);
        acc = __fmaf_rn(en[r][6], e1.z, acc);
        acc = __fmaf_rn(en[r][7], e1.w, acc);
        acc = __fmaf_rn(en[r][8], e2.x, acc);
        acc = __fmaf_rn(en[r][9], e2.y, acc);
        acc = __fmaf_rn(en[r][10], e2.z, acc);
        acc = __fmaf_rn(en[r][11], e2.w, acc);
        acc = __fmaf_rn(en[r][12], e3.x, acc);
        acc = __fmaf_rn(en[r][13], e3.y, acc);
        acc = __fmaf_rn(en[r][14], e3.z, acc);
        acc = __fmaf_rn(en[r][15], e3.w, acc);
        acc = fmaxf(acc, 0.0f);
        g[r][c * JST + j] = acc;
        lmax[r] = fmaxf(lmax[r], acc);
      }
    }
  }
  // no __syncthreads below (waves independent)

  float a_sig = 1.0f / (1.0f + expf(-alpha[0]));
  float oma = 1.0f - a_sig;
  const unsigned long long lt = (1ull << lane) - 1ull;

#pragma unroll
  for (int r = 0; r < RPW; ++r) {
    const int row = nbase + wv * RPW + r;
    // 1) bitonic-sort 64 lane-maxes desc -> th = 20th largest (lower bound on v20)
    float v = lmax[r];
#pragma unroll
    for (int k = 2; k <= 64; k <<= 1) {
#pragma unroll
      for (int m = k >> 1; m > 0; m >>= 1) {
        float o = __shfl_xor(v, m, 64);
        bool up = (lane & k) != 0;
        bool takeMax = ((lane & m) == 0) ^ up;
        v = takeMax ? fmaxf(v, o) : fminf(v, o);
      }
    }
    float th = __shfl(v, 19, 64);

    // 2) ballot-prefix compaction of candidates >= th into LDS
    int base = 0;
#pragma unroll
    for (int j = 0; j < 32; ++j) {
      bool hit = g[r][j] >= th;
      unsigned long long m = __ballot(hit);
      if (hit) {
        int slot = base + __popcll(m & lt);
        if (slot < CCAP) {
          unsigned idx = (unsigned)(lane + 64 * j);
          cand[wv][slot] =
              ((unsigned long long)__float_as_uint(g[r][j]) << 32) | (unsigned)(~idx);
        }
      }
      base += __popcll(m);
    }

    unsigned long long key;
    if (base <= CCAP) {
      asm volatile("s_waitcnt lgkmcnt(0)" ::: "memory");
      key = (lane < base) ? cand[wv][lane] : 0ull;
#pragma unroll
      for (int k = 2; k <= 64; k <<= 1) {
#pragma unroll
        for (int m = k >> 1; m > 0; m >>= 1) {
          unsigned long long o = shflxor64(key, m);
          bool up = (lane & k) != 0;
          bool takeMax = ((lane & m) == 0) ^ up;
          key = (takeMax == (key > o)) ? key : o;
        }
      }
    } else {
      // rare exact fallback (flat rows / ReLU-zero ties): 20x wave argmax
      asm volatile("s_waitcnt lgkmcnt(0)" ::: "memory");
      unsigned taken = 0u;
      for (int sel = 0; sel < NK; ++sel) {
        float bv = -1.0f;
        int bj = 0;
#pragma unroll
        for (int j = 0; j < 32; ++j) {
          bool ok = ((taken >> j) & 1u) == 0u;
          bool bet = ok && (g[r][j] > bv);
          bv = bet ? g[r][j] : bv;
          bj = bet ? j : bj;
        }
        unsigned idx = (unsigned)(lane + 64 * bj);
        unsigned long long kk = ((unsigned long long)__float_as_uint(bv) << 32) | (unsigned)(~idx);
#pragma unroll
        for (int off = 32; off; off >>= 1) {
          unsigned long long o = shflxor64(kk, off);
          kk = (o > kk) ? o : kk;
        }
        unsigned wi = ~(unsigned)kk;
        if ((wi & 63u) == (unsigned)lane) taken |= (1u << (wi >> 6));
        if (lane == 0) cand[wv][sel] = kk;
      }
      asm volatile("s_waitcnt lgkmcnt(0)" ::: "memory");
      key = (lane < NK) ? cand[wv][lane] : 0ull;
    }

    // 3) softmax over the selected 20 (desc-sorted in lanes 0..19)
    float vs = __uint_as_float((unsigned)(key >> 32));
    float vmax = __shfl(vs, 0, 64);
    float ex = (lane < NK) ? expf(vs - vmax) : 0.0f;
    float ssum = ex;
#pragma unroll
    for (int off = 32; off; off >>= 1) ssum += __shfl_xor(ssum, off, 64);
    float w = ex / ssum;

    if (lane < NK) {
      unsigned mi = ~(unsigned)key;
      float ai = aInv[row];
      float p = Ap[(size_t)row * NN + mi];
      size_t o20 = ((size_t)b * NN + row) * NK + lane;
      fixVal[o20] = __fadd_rn(__fmul_rn(p, ai), __fmul_rn(oma, w));
      fixIdx[o20] = (unsigned short)mi;
    }
  }
}

// ---- kernel 3: pure streaming output write --------------------------------
// block = one column-row n; 4 waves x 4 batches each; Ap row read once.
__global__ __launch_bounds__(256, 6) void k_out(
    const float* __restrict__ Ap, const float* __restrict__ aInv,
    const unsigned short* __restrict__ fixIdx, const float* __restrict__ fixVal,
    float* __restrict__ out) {
  const int tid = threadIdx.x;
  const int lane = tid & 63;
  const int q = tid >> 6;
  const int n = blockIdx.x;

  float ai = aInv[n];
  const float4* pr = (const float4*)(Ap + (size_t)n * NN);
  float4 o[8];
#pragma unroll
  for (int f = 0; f < 8; ++f) {
    float4 p = pr[lane + 64 * f];
    o[f].x = __fmul_rn(p.x, ai);
    o[f].y = __fmul_rn(p.y, ai);
    o[f].z = __fmul_rn(p.z, ai);
    o[f].w = __fmul_rn(p.w, ai);
  }

  unsigned short ii[4];
  float vv[4];
#pragma unroll
  for (int i = 0; i < 4; ++i) {
    int bb = q * 4 + i;
    if (lane < NK) {
      size_t o20 = ((size_t)bb * NN + n) * NK + lane;
      ii[i] = fixIdx[o20];
      vv[i] = fixVal[o20];
    }
  }

#pragma unroll
  for (int i = 0; i < 4; ++i) {
    int bb = q * 4 + i;
    float4* orow = (float4*)(out + ((size_t)bb * NN + n) * NN);
#pragma unroll
    for (int f = 0; f < 8; ++f) orow[lane + 64 * f] = o[f];
  }
  // drain base stores before scatter-fixing the 20 sparse positions per row
  asm volatile("s_waitcnt vmcnt(0)" ::: "memory");
#pragma unroll
  for (int i = 0; i < 4; ++i) {
    if (lane < NK) {
      int bb = q * 4 + i;
      out[((size_t)bb * NN + n) * NN + (unsigned)ii[i]] = vv[i];
    }
  }
}

extern "C" void kernel_launch(void* const* d_in, const int* in_sizes, int n_in,
                              void* d_out, int out_size, void* d_ws, size_t ws_size,
                              hipStream_t stream) {
  const float* x = (const float*)d_in[0];
  const float* Ap = (const float*)d_in[1];
  const float* W = (const float*)d_in[2];
  const float* bb = (const float*)d_in[3];
  const float* alpha = (const float*)d_in[4];
  float* out = (float*)d_out;

  float* emb = (float*)d_ws;                                  // 2 MB
  float* aInv = emb + (size_t)NB * NN * NH;                   // 8 KB
  float* fixVal = aInv + NN;                                  // 2.62 MB
  unsigned short* fixIdx = (unsigned short*)(fixVal + (size_t)NB * NN * NK);  // 1.31 MB

  hipLaunchKernelGGL(k_emb, dim3((NB * NN + 255) / 256), dim3(256), 0, stream,
                     x, W, bb, emb);
  hipLaunchKernelGGL(k_rowsum, dim3((NN * 64) / 256), dim3(256), 0, stream,
                     Ap, alpha, aInv);
  hipLaunchKernelGGL(k_topk, dim3(NB * (NN / RPB)), dim3(256), 0, stream,
                     emb, Ap, aInv, alpha, fixIdx, fixVal);
  hipLaunchKernelGGL(k_out, dim3(NN), dim3(256), 0, stream,
                     Ap, aInv, fixIdx, fixVal, out);
}

// Round 3
// 222.452 us; speedup vs baseline: 3.9991x; 3.9991x over previous
//
#include <hip/hip_runtime.h>
#include <math.h>

#define NB 16
#define NT 12
#define NN 2048
#define NH 16
#define NK 20

#define RPWV 16   // rows per wave
#define CCAP 64

static __device__ __forceinline__ unsigned long long shflxor64(unsigned long long v, int m) {
  unsigned lo = (unsigned)v, hi = (unsigned)(v >> 32);
  lo = (unsigned)__shfl_xor((int)lo, m, 64);
  hi = (unsigned)__shfl_xor((int)hi, m, 64);
  return ((unsigned long long)hi << 32) | lo;
}

// one exact FMA order used by pass A, pass B, gather, and fallback:
static __device__ __forceinline__ float dotQ(const float* q, const float4& e0,
                                             const float4& e1, const float4& e2,
                                             const float4& e3) {
  float a = 0.0f;
  a = __fmaf_rn(q[0], e0.x, a);  a = __fmaf_rn(q[1], e0.y, a);
  a = __fmaf_rn(q[2], e0.z, a);  a = __fmaf_rn(q[3], e0.w, a);
  a = __fmaf_rn(q[4], e1.x, a);  a = __fmaf_rn(q[5], e1.y, a);
  a = __fmaf_rn(q[6], e1.z, a);  a = __fmaf_rn(q[7], e1.w, a);
  a = __fmaf_rn(q[8], e2.x, a);  a = __fmaf_rn(q[9], e2.y, a);
  a = __fmaf_rn(q[10], e2.z, a); a = __fmaf_rn(q[11], e2.w, a);
  a = __fmaf_rn(q[12], e3.x, a); a = __fmaf_rn(q[13], e3.y, a);
  a = __fmaf_rn(q[14], e3.z, a); a = __fmaf_rn(q[15], e3.w, a);
  return a;
}

// ---- kernel 0: state mean + 16-dim tanh embedding -------------------------
__global__ void k_emb(const float* __restrict__ x, const float* __restrict__ W,
                      const float* __restrict__ bias, float* __restrict__ emb) {
  int id = blockIdx.x * blockDim.x + threadIdx.x;
  if (id >= NB * NN) return;
  int b = id >> 11, n = id & (NN - 1);
  const float* xp = x + ((size_t)b * NT) * NN + n;
  float s = 0.0f;
#pragma unroll
  for (int t = 0; t < NT; ++t) s += xp[(size_t)t * NN];
  s = s / 12.0f;
  float* e = emb + (size_t)id * NH;
#pragma unroll
  for (int h = 0; h < NH; ++h) {
    float arg = __fadd_rn(__fmul_rn(s, W[h]), bias[h]);
    e[h] = (float)tanh((double)arg);
  }
}

// ---- kernel 1: A_physical row sums -> a / (sum + 1e-8) --------------------
__global__ void k_rowsum(const float* __restrict__ A, const float* __restrict__ alpha,
                         float* __restrict__ aInv) {
  int gw = (blockIdx.x * blockDim.x + threadIdx.x) >> 6;
  int lane = threadIdx.x & 63;
  if (gw >= NN) return;
  const float* row = A + (size_t)gw * NN;
  float s = 0.0f;
#pragma unroll
  for (int j = 0; j < NN / 64; ++j) s += row[lane + 64 * j];
#pragma unroll
  for (int off = 32; off; off >>= 1) s += __shfl_xor(s, off, 64);
  if (lane == 0) {
    float a = 1.0f / (1.0f + expf(-alpha[0]));
    aInv[gw] = a / (s + 1e-8f);
  }
}

// ---- kernel 2: two-pass streaming top-20 + softmax ------------------------
__global__ __launch_bounds__(256) void k_topk(
    const float* __restrict__ emb, const float* __restrict__ Ap,
    const float* __restrict__ aInv, const float* __restrict__ alpha,
    unsigned short* __restrict__ fixIdx, float* __restrict__ fixVal) {
  __shared__ unsigned short candIdx[4][RPWV][CCAP];   // 8 KB
  __shared__ int candCnt[4][RPWV];
  __shared__ float thL[4][RPWV];
  __shared__ unsigned long long fsel[4][NK];

  const int lane = threadIdx.x & 63;
  const int wv = threadIdx.x >> 6;
  const int gw = blockIdx.x * 4 + wv;     // wave id 0..2047
  const int b = gw >> 7;                  // 128 waves per batch
  const int rbase = (gw & 127) * RPWV;
  const float* embB = emb + (size_t)b * NN * NH;

  if (lane < RPWV) candCnt[wv][lane] = 0;

  // ---- pass A: running per-lane max over this lane's 32 nodes ----
  float rmax[RPWV];
#pragma unroll
  for (int r = 0; r < RPWV; ++r) rmax[r] = -1.0f;

#pragma unroll 1
  for (int et = 0; et < 8; ++et) {
    asm volatile("" ::: "memory");  // block LICM from hoisting q loads (spill guard)
    const float* p0 = embB + (size_t)(et * 256 + lane) * NH;
    float4 a0 = *(const float4*)(p0 + 0), a1 = *(const float4*)(p0 + 4),
           a2 = *(const float4*)(p0 + 8), a3 = *(const float4*)(p0 + 12);
    const float* p1 = p0 + 64 * NH;
    float4 b0 = *(const float4*)(p1 + 0), b1 = *(const float4*)(p1 + 4),
           b2 = *(const float4*)(p1 + 8), b3 = *(const float4*)(p1 + 12);
    const float* p2 = p1 + 64 * NH;
    float4 c0 = *(const float4*)(p2 + 0), c1 = *(const float4*)(p2 + 4),
           c2 = *(const float4*)(p2 + 8), c3 = *(const float4*)(p2 + 12);
    const float* p3 = p2 + 64 * NH;
    float4 d0 = *(const float4*)(p3 + 0), d1 = *(const float4*)(p3 + 4),
           d2 = *(const float4*)(p3 + 8), d3 = *(const float4*)(p3 + 12);
#pragma unroll
    for (int r = 0; r < RPWV; ++r) {
      const float* qp = embB + (size_t)(rbase + r) * NH;
      float qv[16];
#pragma unroll
      for (int h = 0; h < 16; ++h) qv[h] = qp[h];
      float v0 = fmaxf(dotQ(qv, a0, a1, a2, a3), 0.0f);
      float v1 = fmaxf(dotQ(qv, b0, b1, b2, b3), 0.0f);
      float v2 = fmaxf(dotQ(qv, c0, c1, c2, c3), 0.0f);
      float v3 = fmaxf(dotQ(qv, d0, d1, d2, d3), 0.0f);
      rmax[r] = fmaxf(rmax[r], fmaxf(fmaxf(v0, v1), fmaxf(v2, v3)));
    }
  }

  // ---- thresholds: th[r] = 20th largest of 64 lane-maxes (<= v20) ----
#pragma unroll 1
  for (int r = 0; r < RPWV; ++r) {
    float v = rmax[r];
#pragma unroll
    for (int k = 2; k <= 64; k <<= 1) {
#pragma unroll
      for (int m = k >> 1; m > 0; m >>= 1) {
        float o = __shfl_xor(v, m, 64);
        bool up = (lane & k) != 0;
        bool takeMax = ((lane & m) == 0) ^ up;
        v = takeMax ? fmaxf(v, o) : fminf(v, o);
      }
    }
    float t19 = __shfl(v, 19, 64);
    if (lane == 0) thL[wv][r] = t19;
  }
  asm volatile("s_waitcnt lgkmcnt(0)" ::: "memory");

  // ---- pass B: identical sweep, compact candidate indices ----
#pragma unroll 1
  for (int et = 0; et < 8; ++et) {
    asm volatile("" ::: "memory");
    const float* p0 = embB + (size_t)(et * 256 + lane) * NH;
    float4 a0 = *(const float4*)(p0 + 0), a1 = *(const float4*)(p0 + 4),
           a2 = *(const float4*)(p0 + 8), a3 = *(const float4*)(p0 + 12);
    const float* p1 = p0 + 64 * NH;
    float4 b0 = *(const float4*)(p1 + 0), b1 = *(const float4*)(p1 + 4),
           b2 = *(const float4*)(p1 + 8), b3 = *(const float4*)(p1 + 12);
    const float* p2 = p1 + 64 * NH;
    float4 c0 = *(const float4*)(p2 + 0), c1 = *(const float4*)(p2 + 4),
           c2 = *(const float4*)(p2 + 8), c3 = *(const float4*)(p2 + 12);
    const float* p3 = p2 + 64 * NH;
    float4 d0 = *(const float4*)(p3 + 0), d1 = *(const float4*)(p3 + 4),
           d2 = *(const float4*)(p3 + 8), d3 = *(const float4*)(p3 + 12);
#pragma unroll
    for (int r = 0; r < RPWV; ++r) {
      const float* qp = embB + (size_t)(rbase + r) * NH;
      float qv[16];
#pragma unroll
      for (int h = 0; h < 16; ++h) qv[h] = qp[h];
      float v0 = fmaxf(dotQ(qv, a0, a1, a2, a3), 0.0f);
      float v1 = fmaxf(dotQ(qv, b0, b1, b2, b3), 0.0f);
      float v2 = fmaxf(dotQ(qv, c0, c1, c2, c3), 0.0f);
      float v3 = fmaxf(dotQ(qv, d0, d1, d2, d3), 0.0f);
      float t = thL[wv][r];
      if (v0 >= t) { int s = atomicAdd(&candCnt[wv][r], 1); if (s < CCAP) candIdx[wv][r][s] = (unsigned short)(et * 256 + lane); }
      if (v1 >= t) { int s = atomicAdd(&candCnt[wv][r], 1); if (s < CCAP) candIdx[wv][r][s] = (unsigned short)(et * 256 + 64 + lane); }
      if (v2 >= t) { int s = atomicAdd(&candCnt[wv][r], 1); if (s < CCAP) candIdx[wv][r][s] = (unsigned short)(et * 256 + 128 + lane); }
      if (v3 >= t) { int s = atomicAdd(&candCnt[wv][r], 1); if (s < CCAP) candIdx[wv][r][s] = (unsigned short)(et * 256 + 192 + lane); }
    }
  }
  asm volatile("s_waitcnt lgkmcnt(0)" ::: "memory");

  // ---- per-row: gather candidates, exact sort, softmax, write fixes ----
  float a_sig = 1.0f / (1.0f + expf(-alpha[0]));
  float oma = 1.0f - a_sig;

#pragma unroll 1
  for (int r = 0; r < RPWV; ++r) {
    const int row = rbase + r;
    const float* qp = embB + (size_t)row * NH;
    float qv[16];
#pragma unroll
    for (int h = 0; h < 16; ++h) qv[h] = qp[h];

    int cnt = __builtin_amdgcn_readfirstlane(candCnt[wv][r]);
    unsigned long long key = 0ull;
    if (cnt <= CCAP) {
      if (lane < cnt) {
        unsigned ci = candIdx[wv][r][lane];
        const float* ep = embB + (size_t)ci * NH;
        float4 e0 = *(const float4*)(ep + 0), e1 = *(const float4*)(ep + 4),
               e2 = *(const float4*)(ep + 8), e3 = *(const float4*)(ep + 12);
        float dd = fmaxf(dotQ(qv, e0, e1, e2, e3), 0.0f);
        key = ((unsigned long long)__float_as_uint(dd) << 32) | (unsigned)(~ci);
      }
#pragma unroll
      for (int k = 2; k <= 64; k <<= 1) {
#pragma unroll
        for (int m = k >> 1; m > 0; m >>= 1) {
          unsigned long long o = shflxor64(key, m);
          bool up = (lane & k) != 0;
          bool takeMax = ((lane & m) == 0) ^ up;
          key = (takeMax == (key > o)) ? key : o;
        }
      }
    } else {
      // rare exact fallback (flat/tied rows): 20x wave argmax with recompute
      unsigned taken = 0u;
#pragma unroll 1
      for (int sel = 0; sel < NK; ++sel) {
        float bv = -1.0f;
        int bs = 0;
#pragma unroll 1
        for (int s = 0; s < 32; ++s) {
          const float* ep = embB + (size_t)(s * 64 + lane) * NH;
          float4 e0 = *(const float4*)(ep + 0), e1 = *(const float4*)(ep + 4),
                 e2 = *(const float4*)(ep + 8), e3 = *(const float4*)(ep + 12);
          float dd = fmaxf(dotQ(qv, e0, e1, e2, e3), 0.0f);
          bool ok = ((taken >> s) & 1u) == 0u;
          bool bet = ok && (dd > bv);
          bv = bet ? dd : bv;
          bs = bet ? s : bs;
        }
        unsigned idx = (unsigned)(bs * 64 + lane);
        unsigned long long kk = ((unsigned long long)__float_as_uint(bv) << 32) | (unsigned)(~idx);
#pragma unroll
        for (int off = 32; off; off >>= 1) {
          unsigned long long o = shflxor64(kk, off);
          kk = (o > kk) ? o : kk;
        }
        unsigned wi = ~(unsigned)kk;
        if ((wi & 63u) == (unsigned)lane) taken |= (1u << (wi >> 6));
        if (lane == 0) fsel[wv][sel] = kk;
      }
      asm volatile("s_waitcnt lgkmcnt(0)" ::: "memory");
      key = (lane < NK) ? fsel[wv][lane] : 0ull;
    }

    // softmax over selected (desc-sorted; lanes 0..19 hold top-20)
    int kl = (cnt < NK) ? cnt : NK;   // cnt >= 20 by construction; defensive
    float vs = __uint_as_float((unsigned)(key >> 32));
    float vmax = __shfl(vs, 0, 64);
    float ex = (lane < kl) ? expf(vs - vmax) : 0.0f;
    float ssum = ex;
#pragma unroll
    for (int off = 32; off; off >>= 1) ssum += __shfl_xor(ssum, off, 64);
    if (lane < kl) {
      float w = ex / ssum;
      unsigned mi = ~(unsigned)key;
      float p = Ap[(size_t)row * NN + mi];
      size_t o20 = ((size_t)b * NN + row) * NK + lane;
      fixVal[o20] = __fadd_rn(__fmul_rn(p, aInv[row]), __fmul_rn(oma, w));
      fixIdx[o20] = (unsigned short)mi;
    }
  }
}

// ---- kernel 3: pure streaming output write --------------------------------
__global__ __launch_bounds__(256, 6) void k_out(
    const float* __restrict__ Ap, const float* __restrict__ aInv,
    const unsigned short* __restrict__ fixIdx, const float* __restrict__ fixVal,
    float* __restrict__ out) {
  const int tid = threadIdx.x;
  const int lane = tid & 63;
  const int q = tid >> 6;
  const int n = blockIdx.x;

  float ai = aInv[n];
  const float4* pr = (const float4*)(Ap + (size_t)n * NN);
  float4 o[8];
#pragma unroll
  for (int f = 0; f < 8; ++f) {
    float4 p = pr[lane + 64 * f];
    o[f].x = __fmul_rn(p.x, ai);
    o[f].y = __fmul_rn(p.y, ai);
    o[f].z = __fmul_rn(p.z, ai);
    o[f].w = __fmul_rn(p.w, ai);
  }

  unsigned short ii[4];
  float vv[4];
#pragma unroll
  for (int i = 0; i < 4; ++i) {
    int bb = q * 4 + i;
    if (lane < NK) {
      size_t o20 = ((size_t)bb * NN + n) * NK + lane;
      ii[i] = fixIdx[o20];
      vv[i] = fixVal[o20];
    }
  }

#pragma unroll
  for (int i = 0; i < 4; ++i) {
    int bb = q * 4 + i;
    float4* orow = (float4*)(out + ((size_t)bb * NN + n) * NN);
#pragma unroll
    for (int f = 0; f < 8; ++f) orow[lane + 64 * f] = o[f];
  }
  asm volatile("s_waitcnt vmcnt(0)" ::: "memory");
#pragma unroll
  for (int i = 0; i < 4; ++i) {
    if (lane < NK) {
      int bb = q * 4 + i;
      out[((size_t)bb * NN + n) * NN + (unsigned)ii[i]] = vv[i];
    }
  }
}

extern "C" void kernel_launch(void* const* d_in, const int* in_sizes, int n_in,
                              void* d_out, int out_size, void* d_ws, size_t ws_size,
                              hipStream_t stream) {
  const float* x = (const float*)d_in[0];
  const float* Ap = (const float*)d_in[1];
  const float* W = (const float*)d_in[2];
  const float* bb = (const float*)d_in[3];
  const float* alpha = (const float*)d_in[4];
  float* out = (float*)d_out;

  float* emb = (float*)d_ws;                                  // 2 MB
  float* aInv = emb + (size_t)NB * NN * NH;                   // 8 KB
  float* fixVal = aInv + NN;                                  // 2.62 MB
  unsigned short* fixIdx = (unsigned short*)(fixVal + (size_t)NB * NN * NK);  // 1.31 MB

  hipLaunchKernelGGL(k_emb, dim3((NB * NN + 255) / 256), dim3(256), 0, stream,
                     x, W, bb, emb);
  hipLaunchKernelGGL(k_rowsum, dim3((NN * 64) / 256), dim3(256), 0, stream,
                     Ap, alpha, aInv);
  hipLaunchKernelGGL(k_topk, dim3(NB * NN / (4 * RPWV)), dim3(256), 0, stream,
                     emb, Ap, aInv, alpha, fixIdx, fixVal);
  hipLaunchKernelGGL(k_out, dim3(NN), dim3(256), 0, stream,
                     Ap, aInv, fixIdx, fixVal, out);
}